// Round 4
// baseline (2054.127 us; speedup 1.0000x reference)
//
#include <hip/hip_runtime.h>
#include <hip/hip_bf16.h>

// BiLSTM: B=64, T=2048, F=128, U=128. fp32 in/out.
// Phase 1: zx[d][bg][t][g][nt][m][lm] (f16) = scale_g * (x@Wx + b'), with
//          per-gate scale {-K, 2K, -K, -K}, K = log2(e), forget bias folded.
// Phase 2: 32 WGs (2 dir x 16 batch-groups of 4), 4 waves (1/SIMD), 2 cells
//          per lane. LDS reads halved vs 8-wave (16 b128/CU-step), h stride
//          144 (2-way max = free). Gates use exp2 directly (args pre-scaled).
//          zc preloaded into MFMA C operand. lgkm-only barrier.

typedef _Float16 half8_t __attribute__((ext_vector_type(8)));
typedef _Float16 half4_t __attribute__((ext_vector_type(4)));
typedef float floatx4 __attribute__((ext_vector_type(4)));

#define T_SEQ 2048
#define GDIM 512
#define KLOG2E 1.4426950408889634f

__device__ __forceinline__ float exp2_f(float x) {
#if __has_builtin(__builtin_amdgcn_exp2f)
    return __builtin_amdgcn_exp2f(x);
#else
    return __expf(x * 0.6931471805599453f);
#endif
}
// sigmoid with pre-negated/scaled arg: x' = -K*x  =>  s = 1/(1+2^x')
__device__ __forceinline__ float sigm2(float x) {
    return __builtin_amdgcn_rcpf(1.0f + exp2_f(x));
}
// tanh with pre-scaled arg: x' = 2K*x  =>  t = 1 - 2/(1+2^x')
__device__ __forceinline__ float tanh2(float x) {
    return 1.0f - 2.0f * __builtin_amdgcn_rcpf(1.0f + exp2_f(x));
}
__device__ __forceinline__ float sel4(floatx4 v, int m) {
    float a = (m & 1) ? v[1] : v[0];
    float b = (m & 1) ? v[3] : v[2];
    return (m & 2) ? b : a;
}

// ---------------- Phase 1: Zx GEMM ----------------
// grid: (32 ttiles, 64 batches, 2 dirs), block 256. A staged once; 4 ctile passes.
__global__ __launch_bounds__(256) void zx_gemm(
    const float* __restrict__ x,
    const float* __restrict__ Wfw, const float* __restrict__ bfw,
    const float* __restrict__ Wbw, const float* __restrict__ bbw,
    _Float16* __restrict__ zx) {
    const int tid = threadIdx.x;
    const int tt = blockIdx.x;           // 0..31
    const int b = blockIdx.y;            // batch
    const int d = blockIdx.z;            // dir
    const int t0 = tt * 64;
    const float* W = d ? Wbw : Wfw;
    const float* bias = d ? bbw : bfw;
    const int bg = b >> 2, m = b & 3;

    __shared__ _Float16 lA[64 * 136];
    __shared__ _Float16 lB[128 * 136];

    // stage A = x[b, t0..t0+63, 0..127] -> lA[row][k]
    const float* xp = x + ((size_t)b * T_SEQ + t0) * 128;
    for (int i = 0; i < 8; ++i) {
        int v = i * 256 + tid;
        int r = v >> 5;
        int kq = (v & 31) << 2;
        float4 f = *(const float4*)(xp + r * 128 + kq);
        half4_t h4;
        h4[0] = (_Float16)f.x; h4[1] = (_Float16)f.y;
        h4[2] = (_Float16)f.z; h4[3] = (_Float16)f.w;
        *(half4_t*)&lA[r * 136 + kq] = h4;
    }

    const int w1 = tid >> 6, lane = tid & 63, lm = lane & 15, q = lane >> 4;

    for (int ct = 0; ct < 4; ++ct) {
        // stage B = W[0..127, ct*128 .. +128) transposed -> lB[col][k]
        const float* wp = W + ct * 128;
        for (int i = 0; i < 16; ++i) {
            int v = i * 256 + tid;
            int k = v >> 5;
            int cq = (v & 31) << 2;
            float4 f = *(const float4*)(wp + (size_t)k * GDIM + cq);
            lB[(cq + 0) * 136 + k] = (_Float16)f.x;
            lB[(cq + 1) * 136 + k] = (_Float16)f.y;
            lB[(cq + 2) * 136 + k] = (_Float16)f.z;
            lB[(cq + 3) * 136 + k] = (_Float16)f.w;
        }
        __syncthreads();

        floatx4 acc[8];
#pragma unroll
        for (int nt = 0; nt < 8; ++nt) acc[nt] = (floatx4){0.f, 0.f, 0.f, 0.f};
#pragma unroll
        for (int ks = 0; ks < 4; ++ks) {
            const int k0 = ks * 32 + q * 8;
            half8_t a = *(const half8_t*)&lA[(w1 * 16 + lm) * 136 + k0];
#pragma unroll
            for (int nt = 0; nt < 8; ++nt) {
                half8_t bf = *(const half8_t*)&lB[(nt * 16 + lm) * 136 + k0];
                acc[nt] = __builtin_amdgcn_mfma_f32_16x16x32_f16(a, bf, acc[nt], 0, 0, 0);
            }
        }
        // store scaled: g = ct; scale i/f/o = -K, j = +2K; forget bias folded.
        const float sc = (ct == 1) ? (2.0f * KLOG2E) : (-KLOG2E);
        const float badd = (ct == 2) ? 1.0f : 0.0f;
#pragma unroll
        for (int nt = 0; nt < 8; ++nt) {
            float bv = bias[ct * 128 + nt * 16 + lm] + badd;
#pragma unroll
            for (int rr = 0; rr < 4; ++rr) {
                int t = t0 + w1 * 16 + q * 4 + rr;
                size_t oi = (((size_t)(d * 16 + bg) * T_SEQ + t) * 4 + ct) * 512
                            + nt * 64 + m * 16 + lm;
                zx[oi] = (_Float16)(sc * (acc[nt][rr] + bv));
            }
        }
        __syncthreads();   // before restaging lB
    }
}

// ---------------- Phase 2: recurrence ----------------
// grid: (16 batch-groups, 2 dirs), block 256 (4 waves, 1/SIMD).
// Wave w owns units w*32 + c*16 + lm, c=0,1 (2 cells/lane, batch = q).
__global__ __launch_bounds__(256, 1) void lstm_rec(
    const float* __restrict__ Wfw, const float* __restrict__ Wbw,
    const _Float16* __restrict__ zx, float* __restrict__ out) {
    const int bg = blockIdx.x;            // 0..15
    const int d = blockIdx.y;             // 0..1
    const int b0 = bg * 4;
    const float* Wd = d ? Wbw : Wfw;
    const int tid = threadIdx.x;
    const int w = tid >> 6, lane = tid & 63, lm = lane & 15, q = lane >> 4;

    __shared__ _Float16 hbuf[2][4 * 144]; // h rows (batch 0..3), stride 144 f16:
                                          // 288B = 72 dw = 8 mod 32 banks ->
                                          // worst 2-way alias on af reads (free)

    // Wh B-fragments: bfr[g][c][ks], col = g*128 + w*32 + c*16 + lm,
    // k = 128 + ks*32 + q*8 + j. Pre-scaled by per-gate exp2 factor.
    half8_t bfr[4][2][4];
#pragma unroll
    for (int g = 0; g < 4; ++g) {
        const float sc = (g == 1) ? (2.0f * KLOG2E) : (-KLOG2E);
#pragma unroll
        for (int c = 0; c < 2; ++c)
#pragma unroll
            for (int ks = 0; ks < 4; ++ks) {
                int col = g * 128 + w * 32 + c * 16 + lm;
                int kb = 128 + ks * 32 + q * 8;
                half8_t f;
#pragma unroll
                for (int j = 0; j < 8; ++j)
                    f[j] = (_Float16)(sc * Wd[(size_t)(kb + j) * GDIM + col]);
                bfr[g][c][ks] = f;
            }
    }

    for (int i = tid; i < 2 * 4 * 144; i += 256) ((_Float16*)hbuf)[i] = (_Float16)0.f;

    // zx prefetch pipeline, depth 3. Per (g,c): zb[t*2048 + g*512 + c*64].
    const _Float16* zb = zx + (size_t)(d * 16 + bg) * T_SEQ * 2048 + w * 128 + lane;
    _Float16 n1[8], n2[8], n3[8];
    {
        int ta = d ? (T_SEQ - 1) : 0;
        int tb = d ? (T_SEQ - 2) : 1;
        int tc = d ? (T_SEQ - 3) : 2;
#pragma unroll
        for (int g = 0; g < 4; ++g)
#pragma unroll
            for (int c = 0; c < 2; ++c) {
                n1[g * 2 + c] = zb[(size_t)ta * 2048 + g * 512 + c * 64];
                n2[g * 2 + c] = zb[(size_t)tb * 2048 + g * 512 + c * 64];
                n3[g * 2 + c] = zb[(size_t)tc * 2048 + g * 512 + c * 64];
            }
    }
    float cst0 = 0.f, cst1 = 0.f;
    __syncthreads();

    for (int s = 0; s < T_SEQ; ++s) {
        const int t = d ? (T_SEQ - 1 - s) : s;
        const _Float16* hr = hbuf[s & 1];
        _Float16* hw = hbuf[(s + 1) & 1];

        // A-fragments: A[row][k] = h[row&3][k] (row-replicated)
        half8_t af[4];
#pragma unroll
        for (int ks = 0; ks < 4; ++ks)
            af[ks] = *(const half8_t*)&hr[(lm & 3) * 144 + ks * 32 + q * 8];

        // rotate zx pipeline; issue prefetch for s+3
        float zc[8];
#pragma unroll
        for (int i = 0; i < 8; ++i) { zc[i] = (float)n1[i]; n1[i] = n2[i]; n2[i] = n3[i]; }
        int sn = (s + 3 < T_SEQ) ? s + 3 : T_SEQ - 1;
        int tn = d ? (T_SEQ - 1 - sn) : sn;
#pragma unroll
        for (int g = 0; g < 4; ++g)
#pragma unroll
            for (int c = 0; c < 2; ++c)
                n3[g * 2 + c] = zb[(size_t)tn * 2048 + g * 512 + c * 64];

        // acc preload = zc broadcast (element q is this lane's cell; rest unused)
        floatx4 acg[4][2];
#pragma unroll
        for (int g = 0; g < 4; ++g)
#pragma unroll
            for (int c = 0; c < 2; ++c) {
                float v = zc[g * 2 + c];
                acg[g][c] = (floatx4){v, v, v, v};
            }
#pragma unroll
        for (int ks = 0; ks < 4; ++ks)
#pragma unroll
            for (int g = 0; g < 4; ++g) {
                acg[g][0] = __builtin_amdgcn_mfma_f32_16x16x32_f16(af[ks], bfr[g][0][ks], acg[g][0], 0, 0, 0);
                acg[g][1] = __builtin_amdgcn_mfma_f32_16x16x32_f16(af[ks], bfr[g][1][ks], acg[g][1], 0, 0, 0);
            }

        // two cells per lane: (batch q, unit w*32+lm) and (batch q, unit w*32+16+lm)
        float zi0 = sel4(acg[0][0], q), zi1 = sel4(acg[0][1], q);
        float zj0 = sel4(acg[1][0], q), zj1 = sel4(acg[1][1], q);
        float zf0 = sel4(acg[2][0], q), zf1 = sel4(acg[2][1], q);
        float zo0 = sel4(acg[3][0], q), zo1 = sel4(acg[3][1], q);
        cst0 = cst0 * sigm2(zf0) + sigm2(zi0) * tanh2(zj0);
        cst1 = cst1 * sigm2(zf1) + sigm2(zi1) * tanh2(zj1);
        float h0 = sigm2(zo0) * tanh2(2.0f * KLOG2E * cst0);
        float h1 = sigm2(zo1) * tanh2(2.0f * KLOG2E * cst1);

        hw[q * 144 + w * 32 + lm] = (_Float16)h0;
        hw[q * 144 + w * 32 + 16 + lm] = (_Float16)h1;
        size_t ob = ((size_t)(b0 + q) * T_SEQ + t) * 256 + d * 128 + w * 32 + lm;
        out[ob] = h0;
        out[ob + 16] = h1;

        // LDS-only barrier (no "memory" clobber -> vmcnt stays in flight).
        __builtin_amdgcn_sched_barrier(0);
        asm volatile("s_waitcnt lgkmcnt(0)");
        __builtin_amdgcn_s_barrier();
        __builtin_amdgcn_sched_barrier(0);
    }
}

extern "C" void kernel_launch(void* const* d_in, const int* in_sizes, int n_in,
                              void* d_out, int out_size, void* d_ws, size_t ws_size,
                              hipStream_t stream) {
    const float* x   = (const float*)d_in[0];
    const float* Wfw = (const float*)d_in[1];
    const float* bfw = (const float*)d_in[2];
    const float* Wbw = (const float*)d_in[3];
    const float* bbw = (const float*)d_in[4];
    float* out = (float*)d_out;
    _Float16* zx = (_Float16*)d_ws;  // 2*16*2048*2048*2B = 256 MiB

    dim3 g1(32, 64, 2);
    zx_gemm<<<g1, 256, 0, stream>>>(x, Wfw, bfw, Wbw, bbw, zx);
    dim3 g2(16, 2);
    lstm_rec<<<g2, 256, 0, stream>>>(Wfw, Wbw, zx, out);
}

// Round 5
// 1444.917 us; speedup vs baseline: 1.4216x; 1.4216x over previous
//
#include <hip/hip_runtime.h>
#include <hip/hip_bf16.h>

// BiLSTM: B=64, T=2048, F=128, U=128. fp32 in/out.
// Phase 1: zx[d][bg][t][g][nt][m][lm] (f16) = scale_g * (x@Wx + b'), with
//          per-gate scale {-K, 2K, -K, -K}, K = log2(e), forget bias folded.
// Phase 2: 32 WGs (2 dir x 16 batch-groups of 4), 8 waves (2/SIMD - the
//          empirically required latency-hiding config), 1 cell/lane.
//          t-loop unrolled x2: prefetch rotation + hbuf parity become
//          register renaming. Uniform (SGPR) addressing for zx loads and
//          out stores. h stride 144 (verified 0 conflicts). lgkm-only
//          barrier keeps zx prefetch + out stores in flight.

typedef _Float16 half8_t __attribute__((ext_vector_type(8)));
typedef _Float16 half4_t __attribute__((ext_vector_type(4)));
typedef float floatx4 __attribute__((ext_vector_type(4)));

#define T_SEQ 2048
#define GDIM 512
#define KLOG2E 1.4426950408889634f

__device__ __forceinline__ float exp2_f(float x) {
#if __has_builtin(__builtin_amdgcn_exp2f)
    return __builtin_amdgcn_exp2f(x);
#else
    return __expf(x * 0.6931471805599453f);
#endif
}
// sigmoid with pre-negated/scaled arg: x' = -K*x  =>  s = 1/(1+2^x')
__device__ __forceinline__ float sigm2(float x) {
    return __builtin_amdgcn_rcpf(1.0f + exp2_f(x));
}
// tanh with pre-scaled arg: x' = 2K*x  =>  t = 1 - 2/(1+2^x')
__device__ __forceinline__ float tanh2(float x) {
    return 1.0f - 2.0f * __builtin_amdgcn_rcpf(1.0f + exp2_f(x));
}
__device__ __forceinline__ float sel4(floatx4 v, int m) {
    float a = (m & 1) ? v[1] : v[0];
    float b = (m & 1) ? v[3] : v[2];
    return (m & 2) ? b : a;
}

// ---------------- Phase 1: Zx GEMM (identical to round-4, verified) --------
// grid: (32 ttiles, 64 batches, 2 dirs), block 256. A staged once; 4 ctile passes.
__global__ __launch_bounds__(256) void zx_gemm(
    const float* __restrict__ x,
    const float* __restrict__ Wfw, const float* __restrict__ bfw,
    const float* __restrict__ Wbw, const float* __restrict__ bbw,
    _Float16* __restrict__ zx) {
    const int tid = threadIdx.x;
    const int tt = blockIdx.x;           // 0..31
    const int b = blockIdx.y;            // batch
    const int d = blockIdx.z;            // dir
    const int t0 = tt * 64;
    const float* W = d ? Wbw : Wfw;
    const float* bias = d ? bbw : bfw;
    const int bg = b >> 2, m = b & 3;

    __shared__ _Float16 lA[64 * 136];
    __shared__ _Float16 lB[128 * 136];

    // stage A = x[b, t0..t0+63, 0..127] -> lA[row][k]
    const float* xp = x + ((size_t)b * T_SEQ + t0) * 128;
    for (int i = 0; i < 8; ++i) {
        int v = i * 256 + tid;
        int r = v >> 5;
        int kq = (v & 31) << 2;
        float4 f = *(const float4*)(xp + r * 128 + kq);
        half4_t h4;
        h4[0] = (_Float16)f.x; h4[1] = (_Float16)f.y;
        h4[2] = (_Float16)f.z; h4[3] = (_Float16)f.w;
        *(half4_t*)&lA[r * 136 + kq] = h4;
    }

    const int w1 = tid >> 6, lane = tid & 63, lm = lane & 15, q = lane >> 4;

    for (int ct = 0; ct < 4; ++ct) {
        // stage B = W[0..127, ct*128 .. +128) transposed -> lB[col][k]
        const float* wp = W + ct * 128;
        for (int i = 0; i < 16; ++i) {
            int v = i * 256 + tid;
            int k = v >> 5;
            int cq = (v & 31) << 2;
            float4 f = *(const float4*)(wp + (size_t)k * GDIM + cq);
            lB[(cq + 0) * 136 + k] = (_Float16)f.x;
            lB[(cq + 1) * 136 + k] = (_Float16)f.y;
            lB[(cq + 2) * 136 + k] = (_Float16)f.z;
            lB[(cq + 3) * 136 + k] = (_Float16)f.w;
        }
        __syncthreads();

        floatx4 acc[8];
#pragma unroll
        for (int nt = 0; nt < 8; ++nt) acc[nt] = (floatx4){0.f, 0.f, 0.f, 0.f};
#pragma unroll
        for (int ks = 0; ks < 4; ++ks) {
            const int k0 = ks * 32 + q * 8;
            half8_t a = *(const half8_t*)&lA[(w1 * 16 + lm) * 136 + k0];
#pragma unroll
            for (int nt = 0; nt < 8; ++nt) {
                half8_t bf = *(const half8_t*)&lB[(nt * 16 + lm) * 136 + k0];
                acc[nt] = __builtin_amdgcn_mfma_f32_16x16x32_f16(a, bf, acc[nt], 0, 0, 0);
            }
        }
        // store scaled: g = ct; scale i/f/o = -K, j = +2K; forget bias folded.
        const float sc = (ct == 1) ? (2.0f * KLOG2E) : (-KLOG2E);
        const float badd = (ct == 2) ? 1.0f : 0.0f;
#pragma unroll
        for (int nt = 0; nt < 8; ++nt) {
            float bv = bias[ct * 128 + nt * 16 + lm] + badd;
#pragma unroll
            for (int rr = 0; rr < 4; ++rr) {
                int t = t0 + w1 * 16 + q * 4 + rr;
                size_t oi = (((size_t)(d * 16 + bg) * T_SEQ + t) * 4 + ct) * 512
                            + nt * 64 + m * 16 + lm;
                zx[oi] = (_Float16)(sc * (acc[nt][rr] + bv));
            }
        }
        __syncthreads();   // before restaging lB
    }
}

// ---------------- Phase 2: recurrence ----------------
// grid: (16 batch-groups, 2 dirs), block 512 (8 waves, 2/SIMD).
// Wave w owns cols {g*128 + w*16 + lm}, g=0..3; batch = q. 1 cell/lane.
__global__ __launch_bounds__(512) void lstm_rec(
    const float* __restrict__ Wfw, const float* __restrict__ Wbw,
    const _Float16* __restrict__ zx, float* __restrict__ out) {
    const int bg = blockIdx.x;            // 0..15
    const int d = blockIdx.y;             // 0..1
    const int b0 = bg * 4;
    const float* Wd = d ? Wbw : Wfw;
    const int tid = threadIdx.x;
    const int w = tid >> 6, lane = tid & 63, lm = lane & 15, q = lane >> 4;
    const int m = q;                      // batch slot of this lane's cell
    const int u = w * 16 + lm;            // unit 0..127

    __shared__ _Float16 hbuf[2][4 * 144]; // h rows (batch 0..3), stride 144 f16:
                                          // af read pattern is worst-case 2-way
                                          // (free); measured 0 conflicts in r4.

    // Wh B-fragments: bfr[g][ks], col = g*128 + u, k = 128 + ks*32 + q*8 + j.
    // Pre-scaled by per-gate exp2 factor {-K, 2K, -K, -K}.
    half8_t bfr[4][4];
#pragma unroll
    for (int g = 0; g < 4; ++g) {
        const float sc = (g == 1) ? (2.0f * KLOG2E) : (-KLOG2E);
#pragma unroll
        for (int ks = 0; ks < 4; ++ks) {
            int col = g * 128 + u;
            int kb = 128 + ks * 32 + q * 8;
            half8_t f;
#pragma unroll
            for (int j = 0; j < 8; ++j)
                f[j] = (_Float16)(sc * Wd[(size_t)(kb + j) * GDIM + col]);
            bfr[g][ks] = f;
        }
    }

    for (int i = tid; i < 2 * 4 * 144; i += 512) ((_Float16*)hbuf)[i] = (_Float16)0.f;

    // zx addressing: zx_d is WAVE-UNIFORM (SGPR base); zoff is a loop-invariant
    // 32-bit per-lane element offset -> saddr-form loads, ~zero per-step VALU.
    const _Float16* zx_d = zx + (size_t)(d * 16 + bg) * T_SEQ * 2048;
    const unsigned zoff = (unsigned)(w * 64 + lane);
    // out addressing: orow = out + t*256 is uniform; obase is per-lane u32.
    const unsigned obase = (unsigned)((b0 + m) * T_SEQ) * 256u + (unsigned)(d * 128 + u);

    // prefetch depth 2, registers na (for step s), nb (for step s+1)
    _Float16 na[4], nb[4];
    {
        const _Float16* r0 = zx_d + (size_t)(d ? (T_SEQ - 1) : 0) * 2048;
        const _Float16* r1 = zx_d + (size_t)(d ? (T_SEQ - 2) : 1) * 2048;
#pragma unroll
        for (int g = 0; g < 4; ++g) na[g] = r0[zoff + g * 512];
#pragma unroll
        for (int g = 0; g < 4; ++g) nb[g] = r1[zoff + g * 512];
    }
    float cst = 0.f;
    __syncthreads();

#define REC_STEP(RD, WR, NREG, SCUR)                                          \
    {                                                                         \
        const int t_ = d ? (T_SEQ - 1 - (SCUR)) : (SCUR);                     \
        half8_t af[4];                                                        \
        _Pragma("unroll")                                                     \
        for (int ks = 0; ks < 4; ++ks)                                        \
            af[ks] = *(const half8_t*)&hbuf[RD][(lm & 3) * 144 + ks * 32 + q * 8]; \
        float zc[4];                                                          \
        _Pragma("unroll")                                                     \
        for (int g = 0; g < 4; ++g) zc[g] = (float)NREG[g];                   \
        int sn_ = (SCUR) + 2; if (sn_ > T_SEQ - 1) sn_ = T_SEQ - 1;           \
        const int tn_ = d ? (T_SEQ - 1 - sn_) : sn_;                          \
        const _Float16* zrow_ = zx_d + (size_t)tn_ * 2048;                    \
        _Pragma("unroll")                                                     \
        for (int g = 0; g < 4; ++g) NREG[g] = zrow_[zoff + g * 512];          \
        floatx4 acg[4];                                                       \
        _Pragma("unroll")                                                     \
        for (int g = 0; g < 4; ++g) acg[g] = (floatx4){0.f, 0.f, 0.f, 0.f};   \
        _Pragma("unroll")                                                     \
        for (int ks = 0; ks < 4; ++ks)                                        \
            _Pragma("unroll")                                                 \
            for (int g = 0; g < 4; ++g)                                       \
                acg[g] = __builtin_amdgcn_mfma_f32_16x16x32_f16(af[ks], bfr[g][ks], acg[g], 0, 0, 0); \
        float zi = sel4(acg[0], m) + zc[0];                                   \
        float zj = sel4(acg[1], m) + zc[1];                                   \
        float zf = sel4(acg[2], m) + zc[2];                                   \
        float zo = sel4(acg[3], m) + zc[3];                                   \
        cst = cst * sigm2(zf) + sigm2(zi) * tanh2(zj);                        \
        float hv = sigm2(zo) * tanh2(2.0f * KLOG2E * cst);                    \
        hbuf[WR][m * 144 + u] = (_Float16)hv;                                 \
        float* orow_ = out + (size_t)t_ * 256;                                \
        orow_[obase] = hv;                                                    \
        __builtin_amdgcn_sched_barrier(0);                                    \
        asm volatile("s_waitcnt lgkmcnt(0)");                                 \
        __builtin_amdgcn_s_barrier();                                         \
        __builtin_amdgcn_sched_barrier(0);                                    \
    }

    for (int s = 0; s < T_SEQ; s += 2) {
        REC_STEP(0, 1, na, s);
        REC_STEP(1, 0, nb, s + 1);
    }
#undef REC_STEP
}

extern "C" void kernel_launch(void* const* d_in, const int* in_sizes, int n_in,
                              void* d_out, int out_size, void* d_ws, size_t ws_size,
                              hipStream_t stream) {
    const float* x   = (const float*)d_in[0];
    const float* Wfw = (const float*)d_in[1];
    const float* bfw = (const float*)d_in[2];
    const float* Wbw = (const float*)d_in[3];
    const float* bbw = (const float*)d_in[4];
    float* out = (float*)d_out;
    _Float16* zx = (_Float16*)d_ws;  // 2*16*2048*2048*2B = 256 MiB

    dim3 g1(32, 64, 2);
    zx_gemm<<<g1, 256, 0, stream>>>(x, Wfw, bfw, Wbw, bbw, zx);
    dim3 g2(16, 2);
    lstm_rec<<<g2, 512, 0, stream>>>(Wfw, Wbw, zx, out);
}